// Round 1
// baseline (3816.442 us; speedup 1.0000x reference)
//
#include <hip/hip_runtime.h>

typedef unsigned short u16;
typedef __attribute__((ext_vector_type(4))) float f32x4;
typedef __attribute__((ext_vector_type(8))) short s16x8;

// ---------- helpers ----------
__device__ __forceinline__ u16 f2bf(float f) {
    union { float f; unsigned u; } v; v.f = f;
    unsigned r = v.u + 0x7FFFu + ((v.u >> 16) & 1u);
    return (u16)(r >> 16);
}

__device__ __forceinline__ void gload_lds16(const u16* g, u16* l) {
    __builtin_amdgcn_global_load_lds(
        (const __attribute__((address_space(1))) unsigned int*)(g),
        (__attribute__((address_space(3))) unsigned int*)(l),
        16, 0, 0);
}

// ---------- constants ----------
#define NTOK 9216      // B*N = 16*576
#define SEQ  576
#define DMODEL 768
#define DFF  3072
#define NHEAD 12
#define HDIM 64

// ---------- convert f32 -> bf16 (grid-stride) ----------
__global__ __launch_bounds__(256) void convert_bf16_kernel(const float* __restrict__ in,
                                                           u16* __restrict__ out, int n) {
    for (int i = blockIdx.x * 256 + threadIdx.x; i < n; i += gridDim.x * 256)
        out[i] = f2bf(in[i]);
}

// ---------- copy f32 (float4 grid-stride) ----------
__global__ __launch_bounds__(256) void copy_f32_kernel(const float* __restrict__ in,
                                                       float* __restrict__ out, int n4) {
    const float4* a = (const float4*)in;
    float4* o = (float4*)out;
    for (int i = blockIdx.x * 256 + threadIdx.x; i < n4; i += gridDim.x * 256)
        o[i] = a[i];
}

// ---------- im2col: x [16,3,384,384] f32 -> [9216,768] bf16 ----------
__global__ __launch_bounds__(256) void im2col_kernel(const float* __restrict__ x,
                                                     u16* __restrict__ out) {
    int tok = blockIdx.x;           // 0..9215
    int b = tok / SEQ, n = tok % SEQ;
    int gy = n / 24, gx = n % 24;
    int tid = threadIdx.x;
#pragma unroll
    for (int j = 0; j < 3; ++j) {
        int col = tid + j * 256;
        int c = col >> 8, py = (col >> 4) & 15, px = col & 15;
        float v = x[(size_t)((b * 3 + c) * 384 + gy * 16 + py) * 384 + gx * 16 + px];
        out[(size_t)tok * DMODEL + col] = f2bf(v);
    }
}

// ---------- per-layer weight transpose + bf16 convert ----------
// qw,kw,vw: [768][768] -> [768][768]^T ; w1: [768][3072] -> [3072][768] ; w2: [3072][768] -> [768][3072]
__global__ __launch_bounds__(256) void transpose_layer_kernel(
        const float* __restrict__ qw, const float* __restrict__ kw, const float* __restrict__ vw,
        const float* __restrict__ w1, const float* __restrict__ w2,
        u16* __restrict__ wTq, u16* __restrict__ wTk, u16* __restrict__ wTv,
        u16* __restrict__ w1T, u16* __restrict__ w2T) {
    int bid = blockIdx.x;
    const float* src; u16* dst; int Kd, Nd, tile;
    if (bid < 1728)      { int m = bid / 576; src = m == 0 ? qw : (m == 1 ? kw : vw);
                           dst = m == 0 ? wTq : (m == 1 ? wTk : wTv); Kd = 768; Nd = 768; tile = bid % 576; }
    else if (bid < 4032) { src = w1; dst = w1T; Kd = 768; Nd = 3072; tile = bid - 1728; }
    else                 { src = w2; dst = w2T; Kd = 3072; Nd = 768; tile = bid - 4032; }
    int ntx = Nd / 32;
    int tk = (tile / ntx) * 32, tn = (tile % ntx) * 32;
    __shared__ float ts[32][33];
    int tx = threadIdx.x & 31, ty = threadIdx.x >> 5;  // ty 0..7
#pragma unroll
    for (int j = 0; j < 32; j += 8)
        ts[ty + j][tx] = src[(size_t)(tk + ty + j) * Nd + tn + tx];
    __syncthreads();
#pragma unroll
    for (int j = 0; j < 32; j += 8)
        dst[(size_t)(tn + ty + j) * Kd + tk + tx] = f2bf(ts[tx][ty + j]);
}

// ---------- LN (row=768) -> bf16 ----------
__global__ __launch_bounds__(256) void ln_bf16_kernel(const float* __restrict__ X,
                                                      const float* __restrict__ w,
                                                      const float* __restrict__ b,
                                                      u16* __restrict__ Y) {
    int row = blockIdx.x, tid = threadIdx.x;
    const float* x = X + (size_t)row * DMODEL;
    float v0 = x[tid], v1 = x[tid + 256], v2 = x[tid + 512];
    float s = v0 + v1 + v2, sq = v0 * v0 + v1 * v1 + v2 * v2;
#pragma unroll
    for (int off = 32; off >= 1; off >>= 1) { s += __shfl_down(s, off); sq += __shfl_down(sq, off); }
    __shared__ float red[8];
    if ((tid & 63) == 0) { red[tid >> 6] = s; red[4 + (tid >> 6)] = sq; }
    __syncthreads();
    float S = red[0] + red[1] + red[2] + red[3];
    float Q = red[4] + red[5] + red[6] + red[7];
    float mean = S * (1.f / DMODEL);
    float var = Q * (1.f / DMODEL) - mean * mean;
    float inv = rsqrtf(var + 1e-5f);
    u16* y = Y + (size_t)row * DMODEL;
    y[tid]       = f2bf((v0 - mean) * inv * w[tid]       + b[tid]);
    y[tid + 256] = f2bf((v1 - mean) * inv * w[tid + 256] + b[tid + 256]);
    y[tid + 512] = f2bf((v2 - mean) * inv * w[tid + 512] + b[tid + 512]);
}

// ---------- LN in place + add pos (t = LN(t)+pos[row%576]) ----------
__global__ __launch_bounds__(256) void ln_add_pos_kernel(float* __restrict__ T,
                                                         const float* __restrict__ w,
                                                         const float* __restrict__ b,
                                                         const float* __restrict__ posln) {
    int row = blockIdx.x, tid = threadIdx.x;
    float* x = T + (size_t)row * DMODEL;
    const float* p = posln + (size_t)(row % SEQ) * DMODEL;
    float v0 = x[tid], v1 = x[tid + 256], v2 = x[tid + 512];
    float s = v0 + v1 + v2, sq = v0 * v0 + v1 * v1 + v2 * v2;
#pragma unroll
    for (int off = 32; off >= 1; off >>= 1) { s += __shfl_down(s, off); sq += __shfl_down(sq, off); }
    __shared__ float red[8];
    if ((tid & 63) == 0) { red[tid >> 6] = s; red[4 + (tid >> 6)] = sq; }
    __syncthreads();
    float S = red[0] + red[1] + red[2] + red[3];
    float Q = red[4] + red[5] + red[6] + red[7];
    float mean = S * (1.f / DMODEL);
    float var = Q * (1.f / DMODEL) - mean * mean;
    float inv = rsqrtf(var + 1e-5f);
    x[tid]       = (v0 - mean) * inv * w[tid]       + b[tid]       + p[tid];
    x[tid + 256] = (v1 - mean) * inv * w[tid + 256] + b[tid + 256] + p[tid + 256];
    x[tid + 512] = (v2 - mean) * inv * w[tid + 512] + b[tid + 512] + p[tid + 512];
}

// ---------- pos embedding: sum, LN, write posln + broadcast to out2 ----------
__global__ __launch_bounds__(256) void pos_ln_kernel(const float* __restrict__ py,
                                                     const float* __restrict__ px,
                                                     const float* __restrict__ w,
                                                     const float* __restrict__ b,
                                                     const int* __restrict__ xs_p,
                                                     const int* __restrict__ ys_p,
                                                     float* __restrict__ posln,
                                                     float* __restrict__ out2) {
    int row = blockIdx.x;  // 0..575
    int gy = row / 24, gx = row % 24;
    int ys = ys_p[0], xs = xs_p[0];
    int tid = threadIdx.x;
    float v[3]; float s = 0.f, sq = 0.f;
#pragma unroll
    for (int j = 0; j < 3; ++j) {
        int c = tid + j * 256;
        v[j] = py[(size_t)(gy + ys) * DMODEL + c] + px[(size_t)(gx + xs) * DMODEL + c];
        s += v[j]; sq += v[j] * v[j];
    }
#pragma unroll
    for (int off = 32; off >= 1; off >>= 1) { s += __shfl_down(s, off); sq += __shfl_down(sq, off); }
    __shared__ float red[8];
    if ((tid & 63) == 0) { red[tid >> 6] = s; red[4 + (tid >> 6)] = sq; }
    __syncthreads();
    float S = red[0] + red[1] + red[2] + red[3];
    float Q = red[4] + red[5] + red[6] + red[7];
    float mean = S * (1.f / DMODEL);
    float var = Q * (1.f / DMODEL) - mean * mean;
    float inv = rsqrtf(var + 1e-5f);
#pragma unroll
    for (int j = 0; j < 3; ++j) {
        int c = tid + j * 256;
        float y = (v[j] - mean) * inv * w[c] + b[c];
        posln[(size_t)row * DMODEL + c] = y;
        for (int bb = 0; bb < 16; ++bb)
            out2[((size_t)bb * SEQ + row) * DMODEL + c] = y;
    }
}

// ---------- GEMM: C[M,N] = A[M,K] @ Bt[N,K]^T  (bf16 in, f32 acc) ----------
#define EPI_CONV 0
#define EPI_BF16 1
#define EPI_VT   2
#define EPI_FFN1 3
#define EPI_FFN2 4

template <int EPI>
__global__ __launch_bounds__(256) void gemm_bt(const u16* __restrict__ A,
                                               const u16* __restrict__ Bt,
                                               float* __restrict__ outF,
                                               u16* __restrict__ outB,
                                               const float* __restrict__ bias,
                                               int M, int N, int K) {
    __shared__ __align__(16) u16 As[128 * 32];
    __shared__ __align__(16) u16 Bs[128 * 32];
    const int tid = threadIdx.x;
    const int wave = tid >> 6, lane = tid & 63;
    const int c_lo = lane & 15, c_hi = lane >> 4;
    const int m0 = blockIdx.x * 128, n0 = blockIdx.y * 128;
    const int wr = (wave >> 1) * 64, wc = (wave & 1) * 64;
    f32x4 acc[4][4] = {};
    for (int k0 = 0; k0 < K; k0 += 32) {
        __syncthreads();
#pragma unroll
        for (int i = 0; i < 2; ++i) {
            int c = i * 256 + tid;
            int row = c >> 2, slot = (c & 3) * 8;
            u16* lbase_a = (u16*)((char*)As + (i * 4 + wave) * 1024);
            u16* lbase_b = (u16*)((char*)Bs + (i * 4 + wave) * 1024);
            gload_lds16(A + (size_t)(m0 + row) * K + k0 + slot, lbase_a);
            gload_lds16(Bt + (size_t)(n0 + row) * K + k0 + slot, lbase_b);
        }
        __syncthreads();
        s16x8 af[4], bf[4];
#pragma unroll
        for (int m = 0; m < 4; ++m)
            af[m] = *(const s16x8*)&As[(wr + m * 16 + c_lo) * 32 + c_hi * 8];
#pragma unroll
        for (int n = 0; n < 4; ++n)
            bf[n] = *(const s16x8*)&Bs[(wc + n * 16 + c_lo) * 32 + c_hi * 8];
#pragma unroll
        for (int m = 0; m < 4; ++m)
#pragma unroll
            for (int n = 0; n < 4; ++n)
                acc[m][n] = __builtin_amdgcn_mfma_f32_16x16x32_bf16(af[m], bf[n], acc[m][n], 0, 0, 0);
    }
    // epilogue: lane holds C[row=(lane>>4)*4+r][col=lane&15] per 16x16 frag
#pragma unroll
    for (int m = 0; m < 4; ++m)
#pragma unroll
        for (int n = 0; n < 4; ++n)
#pragma unroll
            for (int r = 0; r < 4; ++r) {
                int grow = m0 + wr + m * 16 + c_hi * 4 + r;
                int gcol = n0 + wc + n * 16 + c_lo;
                float v = acc[m][n][r];
                if (EPI == EPI_CONV) {
                    v += bias[gcol]; v = fmaxf(v, 0.f);
                    outF[(size_t)grow * N + gcol] = v;
                } else if (EPI == EPI_BF16) {
                    outB[(size_t)grow * N + gcol] = f2bf(v);
                } else if (EPI == EPI_VT) {
                    int b = grow / SEQ, nt = grow % SEQ;
                    int h = gcol >> 6, dh = gcol & 63;
                    outB[(size_t)(((b * NHEAD + h) << 6) + dh) * SEQ + nt] = f2bf(v);
                } else if (EPI == EPI_FFN1) {
                    v += bias[gcol]; v = fmaxf(v, 0.f);
                    outB[(size_t)grow * N + gcol] = f2bf(v);
                } else if (EPI == EPI_FFN2) {
                    outF[(size_t)grow * DMODEL + gcol] += v + bias[gcol];
                }
            }
}

// ---------- flash attention: grid = B*NH*9, block 256 (4 waves x 16 q-rows) ----------
__global__ __launch_bounds__(256) void attn_kernel(const u16* __restrict__ Qb,
                                                   const u16* __restrict__ Kb,
                                                   const u16* __restrict__ Vt,
                                                   float* __restrict__ T) {
    int bid = blockIdx.x;
    int qt = bid % 9, h = (bid / 9) % NHEAD, b = bid / (9 * NHEAD);
    int q0 = qt * 64;
    const int tid = threadIdx.x, wave = tid >> 6, lane = tid & 63;
    const int c_lo = lane & 15, c_hi = lane >> 4;
    __shared__ __align__(16) u16 Qs[64][72];
    __shared__ __align__(16) u16 Ks[64][72];
    __shared__ __align__(16) u16 Vs[64][72];
    __shared__ __align__(16) u16 Ps[4][16][72];
    // stage Q tile (rows q0..q0+64, cols h*64..h*64+64)
#pragma unroll
    for (int i = 0; i < 2; ++i) {
        int c = i * 256 + tid, row = c >> 3, slot = (c & 7) * 8;
        *(s16x8*)&Qs[row][slot] =
            *(const s16x8*)(Qb + ((size_t)(b * SEQ + q0 + row) * DMODEL + h * HDIM + slot));
    }
    f32x4 o[4] = {};
    float mrun[4], lrun[4];
#pragma unroll
    for (int r = 0; r < 4; ++r) { mrun[r] = -1e30f; lrun[r] = 0.f; }
    for (int t2 = 0; t2 < 9; ++t2) {
        int kv0 = t2 * 64;
        __syncthreads();
#pragma unroll
        for (int i = 0; i < 2; ++i) {
            int c = i * 256 + tid, row = c >> 3, slot = (c & 7) * 8;
            *(s16x8*)&Ks[row][slot] =
                *(const s16x8*)(Kb + ((size_t)(b * SEQ + kv0 + row) * DMODEL + h * HDIM + slot));
            *(s16x8*)&Vs[row][slot] =
                *(const s16x8*)(Vt + ((size_t)((b * NHEAD + h) * HDIM + row) * SEQ + kv0 + slot));
        }
        __syncthreads();
        // S = Q K^T for this wave's 16 q rows
        f32x4 s[4] = {};
        s16x8 aq[2];
#pragma unroll
        for (int ks = 0; ks < 2; ++ks)
            aq[ks] = *(const s16x8*)&Qs[wave * 16 + c_lo][ks * 32 + c_hi * 8];
#pragma unroll
        for (int nf = 0; nf < 4; ++nf)
#pragma unroll
            for (int ks = 0; ks < 2; ++ks) {
                s16x8 bk = *(const s16x8*)&Ks[nf * 16 + c_lo][ks * 32 + c_hi * 8];
                s[nf] = __builtin_amdgcn_mfma_f32_16x16x32_bf16(aq[ks], bk, s[nf], 0, 0, 0);
            }
#pragma unroll
        for (int nf = 0; nf < 4; ++nf)
#pragma unroll
            for (int r = 0; r < 4; ++r) s[nf][r] *= 0.125f;  // 1/sqrt(64)
        // online softmax
        float mx[4];
#pragma unroll
        for (int r = 0; r < 4; ++r)
            mx[r] = fmaxf(fmaxf(s[0][r], s[1][r]), fmaxf(s[2][r], s[3][r]));
#pragma unroll
        for (int off = 1; off < 16; off <<= 1)
#pragma unroll
            for (int r = 0; r < 4; ++r) mx[r] = fmaxf(mx[r], __shfl_xor(mx[r], off));
        float alpha[4];
#pragma unroll
        for (int r = 0; r < 4; ++r) {
            float mn = fmaxf(mrun[r], mx[r]);
            alpha[r] = __expf(mrun[r] - mn);
            mrun[r] = mn;
            lrun[r] *= alpha[r];
        }
        float ls[4] = {0.f, 0.f, 0.f, 0.f};
        u16 pb[4][4];
#pragma unroll
        for (int nf = 0; nf < 4; ++nf)
#pragma unroll
            for (int r = 0; r < 4; ++r) {
                float p = __expf(s[nf][r] - mrun[r]);
                ls[r] += p;
                pb[nf][r] = f2bf(p);
            }
#pragma unroll
        for (int off = 1; off < 16; off <<= 1)
#pragma unroll
            for (int r = 0; r < 4; ++r) ls[r] += __shfl_xor(ls[r], off);
#pragma unroll
        for (int r = 0; r < 4; ++r) lrun[r] += ls[r];
#pragma unroll
        for (int df = 0; df < 4; ++df)
#pragma unroll
            for (int r = 0; r < 4; ++r) o[df][r] *= alpha[r];
        // bounce P through per-wave LDS to get A-operand layout
#pragma unroll
        for (int nf = 0; nf < 4; ++nf)
#pragma unroll
            for (int r = 0; r < 4; ++r)
                Ps[wave][c_hi * 4 + r][c_lo + nf * 16] = pb[nf][r];
        asm volatile("s_waitcnt lgkmcnt(0)" ::: "memory");
        s16x8 pa[2];
#pragma unroll
        for (int ks = 0; ks < 2; ++ks)
            pa[ks] = *(const s16x8*)&Ps[wave][c_lo][ks * 32 + c_hi * 8];
#pragma unroll
        for (int df = 0; df < 4; ++df)
#pragma unroll
            for (int ks = 0; ks < 2; ++ks) {
                s16x8 bv = *(const s16x8*)&Vs[df * 16 + c_lo][ks * 32 + c_hi * 8];
                o[df] = __builtin_amdgcn_mfma_f32_16x16x32_bf16(pa[ks], bv, o[df], 0, 0, 0);
            }
    }
    // t += O / l
#pragma unroll
    for (int df = 0; df < 4; ++df)
#pragma unroll
        for (int r = 0; r < 4; ++r) {
            int grow = b * SEQ + q0 + wave * 16 + c_hi * 4 + r;
            int gcol = h * HDIM + df * 16 + c_lo;
            T[(size_t)grow * DMODEL + gcol] += o[df][r] / lrun[r];
        }
}

// ---------- host ----------
extern "C" void kernel_launch(void* const* d_in, const int* in_sizes, int n_in,
                              void* d_out, int out_size, void* d_ws, size_t ws_size,
                              hipStream_t stream) {
    (void)in_sizes; (void)n_in; (void)out_size; (void)ws_size;
    const float* x        = (const float*)d_in[0];
    const float* conv_w   = (const float*)d_in[1];
    const float* conv_b   = (const float*)d_in[2];
    const float* ln_w     = (const float*)d_in[3];
    const float* ln_b     = (const float*)d_in[4];
    const float* pos_y    = (const float*)d_in[5];
    const float* pos_x    = (const float*)d_in[6];
    const float* mha_ln_w = (const float*)d_in[7];
    const float* mha_ln_b = (const float*)d_in[8];
    const float* qw       = (const float*)d_in[9];
    const float* kw       = (const float*)d_in[10];
    const float* vw       = (const float*)d_in[11];
    const float* ffn_ln_w = (const float*)d_in[12];
    const float* ffn_ln_b = (const float*)d_in[13];
    const float* w1       = (const float*)d_in[14];
    const float* b1       = (const float*)d_in[15];
    const float* w2       = (const float*)d_in[16];
    const float* b2       = (const float*)d_in[17];
    const int*   xs       = (const int*)d_in[18];
    const int*   ys       = (const int*)d_in[19];
    float* out1 = (float*)d_out;
    float* out2 = out1 + (size_t)NTOK * DMODEL;

    size_t off = 0;
    char* ws = (char*)d_ws;
    auto carve = [&](size_t bytes) { char* p = ws + off; off += (bytes + 255) & ~(size_t)255; return p; };
    u16* wTq = (u16*)carve((size_t)768 * 768 * 2);
    u16* wTk = (u16*)carve((size_t)768 * 768 * 2);
    u16* wTv = (u16*)carve((size_t)768 * 768 * 2);
    u16* w1T = (u16*)carve((size_t)DFF * DMODEL * 2);
    u16* w2T = (u16*)carve((size_t)DMODEL * DFF * 2);
    float* t  = (float*)carve((size_t)NTOK * DMODEL * 4);
    u16* tl   = (u16*)carve((size_t)NTOK * DMODEL * 2);
    u16* qb   = (u16*)carve((size_t)NTOK * DMODEL * 2);
    u16* kb   = (u16*)carve((size_t)NTOK * DMODEL * 2);
    u16* vT   = (u16*)carve((size_t)NTOK * DMODEL * 2);
    u16* hb   = (u16*)carve((size_t)NTOK * DFF * 2);
    float* posln = (float*)carve((size_t)SEQ * DMODEL * 4);
    u16* cw   = wTq;   // alias: conv weight bf16 lives in wTq region pre-loop
    u16* im2c = hb;    // alias: im2col lives in hb region pre-loop

    convert_bf16_kernel<<<1152, 256, 0, stream>>>(conv_w, cw, 768 * 768);
    im2col_kernel<<<NTOK, 256, 0, stream>>>(x, im2c);
    gemm_bt<EPI_CONV><<<dim3(72, 6), 256, 0, stream>>>(im2c, cw, t, nullptr, conv_b, NTOK, DMODEL, DMODEL);
    pos_ln_kernel<<<SEQ, 256, 0, stream>>>(pos_y, pos_x, ln_w, ln_b, xs, ys, posln, out2);
    ln_add_pos_kernel<<<NTOK, 256, 0, stream>>>(t, ln_w, ln_b, posln);

    for (int i = 0; i < 12; ++i) {
        transpose_layer_kernel<<<6336, 256, 0, stream>>>(
            qw + (size_t)i * 768 * 768, kw + (size_t)i * 768 * 768, vw + (size_t)i * 768 * 768,
            w1 + (size_t)i * 768 * DFF, w2 + (size_t)i * DFF * 768,
            wTq, wTk, wTv, w1T, w2T);
        ln_bf16_kernel<<<NTOK, 256, 0, stream>>>(t, mha_ln_w + i * DMODEL, mha_ln_b + i * DMODEL, tl);
        gemm_bt<EPI_BF16><<<dim3(72, 6), 256, 0, stream>>>(tl, wTq, nullptr, qb, nullptr, NTOK, DMODEL, DMODEL);
        gemm_bt<EPI_BF16><<<dim3(72, 6), 256, 0, stream>>>(tl, wTk, nullptr, kb, nullptr, NTOK, DMODEL, DMODEL);
        gemm_bt<EPI_VT>  <<<dim3(72, 6), 256, 0, stream>>>(tl, wTv, nullptr, vT, nullptr, NTOK, DMODEL, DMODEL);
        attn_kernel<<<16 * NHEAD * 9, 256, 0, stream>>>(qb, kb, vT, t);
        ln_bf16_kernel<<<NTOK, 256, 0, stream>>>(t, ffn_ln_w + i * DMODEL, ffn_ln_b + i * DMODEL, tl);
        gemm_bt<EPI_FFN1><<<dim3(72, 24), 256, 0, stream>>>(tl, w1T, nullptr, hb, b1 + i * DFF, NTOK, DFF, DMODEL);
        gemm_bt<EPI_FFN2><<<dim3(72, 6), 256, 0, stream>>>(hb, w2T, t, nullptr, b2 + i * DMODEL, NTOK, DMODEL, DFF);
    }
    copy_f32_kernel<<<2048, 256, 0, stream>>>(t, out1, (NTOK * DMODEL) / 4);
}

// Round 2
// 3255.621 us; speedup vs baseline: 1.1723x; 1.1723x over previous
//
#include <hip/hip_runtime.h>

typedef unsigned short u16;
typedef __attribute__((ext_vector_type(4))) float f32x4;
typedef __attribute__((ext_vector_type(8))) short s16x8;

// ---------- helpers ----------
__device__ __forceinline__ u16 f2bf(float f) {
    union { float f; unsigned u; } v; v.f = f;
    unsigned r = v.u + 0x7FFFu + ((v.u >> 16) & 1u);
    return (u16)(r >> 16);
}

__device__ __forceinline__ void gload_lds16(const u16* g, u16* l) {
    __builtin_amdgcn_global_load_lds(
        (const __attribute__((address_space(1))) unsigned int*)(g),
        (__attribute__((address_space(3))) unsigned int*)(l),
        16, 0, 0);
}

// ---------- constants ----------
#define NTOK 9216      // B*N = 16*576
#define SEQ  576
#define DMODEL 768
#define DFF  3072
#define NHEAD 12
#define HDIM 64

// ---------- convert f32 -> bf16 (grid-stride) ----------
__global__ __launch_bounds__(256) void convert_bf16_kernel(const float* __restrict__ in,
                                                           u16* __restrict__ out, int n) {
    for (int i = blockIdx.x * 256 + threadIdx.x; i < n; i += gridDim.x * 256)
        out[i] = f2bf(in[i]);
}

// ---------- copy f32 (float4 grid-stride) ----------
__global__ __launch_bounds__(256) void copy_f32_kernel(const float* __restrict__ in,
                                                       float* __restrict__ out, int n4) {
    const float4* a = (const float4*)in;
    float4* o = (float4*)out;
    for (int i = blockIdx.x * 256 + threadIdx.x; i < n4; i += gridDim.x * 256)
        o[i] = a[i];
}

// ---------- im2col: x [16,3,384,384] f32 -> [9216,768] bf16 ----------
__global__ __launch_bounds__(256) void im2col_kernel(const float* __restrict__ x,
                                                     u16* __restrict__ out) {
    int tok = blockIdx.x;           // 0..9215
    int b = tok / SEQ, n = tok % SEQ;
    int gy = n / 24, gx = n % 24;
    int tid = threadIdx.x;
#pragma unroll
    for (int j = 0; j < 3; ++j) {
        int col = tid + j * 256;
        int c = col >> 8, py = (col >> 4) & 15, px = col & 15;
        float v = x[(size_t)((b * 3 + c) * 384 + gy * 16 + py) * 384 + gx * 16 + px];
        out[(size_t)tok * DMODEL + col] = f2bf(v);
    }
}

// ---------- per-layer weight transpose + bf16 convert ----------
__global__ __launch_bounds__(256) void transpose_layer_kernel(
        const float* __restrict__ qw, const float* __restrict__ kw, const float* __restrict__ vw,
        const float* __restrict__ w1, const float* __restrict__ w2,
        u16* __restrict__ wTq, u16* __restrict__ wTk, u16* __restrict__ wTv,
        u16* __restrict__ w1T, u16* __restrict__ w2T) {
    int bid = blockIdx.x;
    const float* src; u16* dst; int Kd, Nd, tile;
    if (bid < 1728)      { int m = bid / 576; src = m == 0 ? qw : (m == 1 ? kw : vw);
                           dst = m == 0 ? wTq : (m == 1 ? wTk : wTv); Kd = 768; Nd = 768; tile = bid % 576; }
    else if (bid < 4032) { src = w1; dst = w1T; Kd = 768; Nd = 3072; tile = bid - 1728; }
    else                 { src = w2; dst = w2T; Kd = 3072; Nd = 768; tile = bid - 4032; }
    int ntx = Nd / 32;
    int tk = (tile / ntx) * 32, tn = (tile % ntx) * 32;
    __shared__ float ts[32][33];
    int tx = threadIdx.x & 31, ty = threadIdx.x >> 5;
#pragma unroll
    for (int j = 0; j < 32; j += 8)
        ts[ty + j][tx] = src[(size_t)(tk + ty + j) * Nd + tn + tx];
    __syncthreads();
#pragma unroll
    for (int j = 0; j < 32; j += 8)
        dst[(size_t)(tn + ty + j) * Kd + tk + tx] = f2bf(ts[tx][ty + j]);
}

// ---------- LN (row=768) -> bf16 ----------
__global__ __launch_bounds__(256) void ln_bf16_kernel(const float* __restrict__ X,
                                                      const float* __restrict__ w,
                                                      const float* __restrict__ b,
                                                      u16* __restrict__ Y) {
    int row = blockIdx.x, tid = threadIdx.x;
    const float* x = X + (size_t)row * DMODEL;
    float v0 = x[tid], v1 = x[tid + 256], v2 = x[tid + 512];
    float s = v0 + v1 + v2, sq = v0 * v0 + v1 * v1 + v2 * v2;
#pragma unroll
    for (int off = 32; off >= 1; off >>= 1) { s += __shfl_down(s, off); sq += __shfl_down(sq, off); }
    __shared__ float red[8];
    if ((tid & 63) == 0) { red[tid >> 6] = s; red[4 + (tid >> 6)] = sq; }
    __syncthreads();
    float S = red[0] + red[1] + red[2] + red[3];
    float Q = red[4] + red[5] + red[6] + red[7];
    float mean = S * (1.f / DMODEL);
    float var = Q * (1.f / DMODEL) - mean * mean;
    float inv = rsqrtf(var + 1e-5f);
    u16* y = Y + (size_t)row * DMODEL;
    y[tid]       = f2bf((v0 - mean) * inv * w[tid]       + b[tid]);
    y[tid + 256] = f2bf((v1 - mean) * inv * w[tid + 256] + b[tid + 256]);
    y[tid + 512] = f2bf((v2 - mean) * inv * w[tid + 512] + b[tid + 512]);
}

// ---------- LN in place + add pos ----------
__global__ __launch_bounds__(256) void ln_add_pos_kernel(float* __restrict__ T,
                                                         const float* __restrict__ w,
                                                         const float* __restrict__ b,
                                                         const float* __restrict__ posln) {
    int row = blockIdx.x, tid = threadIdx.x;
    float* x = T + (size_t)row * DMODEL;
    const float* p = posln + (size_t)(row % SEQ) * DMODEL;
    float v0 = x[tid], v1 = x[tid + 256], v2 = x[tid + 512];
    float s = v0 + v1 + v2, sq = v0 * v0 + v1 * v1 + v2 * v2;
#pragma unroll
    for (int off = 32; off >= 1; off >>= 1) { s += __shfl_down(s, off); sq += __shfl_down(sq, off); }
    __shared__ float red[8];
    if ((tid & 63) == 0) { red[tid >> 6] = s; red[4 + (tid >> 6)] = sq; }
    __syncthreads();
    float S = red[0] + red[1] + red[2] + red[3];
    float Q = red[4] + red[5] + red[6] + red[7];
    float mean = S * (1.f / DMODEL);
    float var = Q * (1.f / DMODEL) - mean * mean;
    float inv = rsqrtf(var + 1e-5f);
    x[tid]       = (v0 - mean) * inv * w[tid]       + b[tid]       + p[tid];
    x[tid + 256] = (v1 - mean) * inv * w[tid + 256] + b[tid + 256] + p[tid + 256];
    x[tid + 512] = (v2 - mean) * inv * w[tid + 512] + b[tid + 512] + p[tid + 512];
}

// ---------- pos embedding: sum, LN, write posln + broadcast to out2 ----------
__global__ __launch_bounds__(256) void pos_ln_kernel(const float* __restrict__ py,
                                                     const float* __restrict__ px,
                                                     const float* __restrict__ w,
                                                     const float* __restrict__ b,
                                                     const int* __restrict__ xs_p,
                                                     const int* __restrict__ ys_p,
                                                     float* __restrict__ posln,
                                                     float* __restrict__ out2) {
    int row = blockIdx.x;
    int gy = row / 24, gx = row % 24;
    int ys = ys_p[0], xs = xs_p[0];
    int tid = threadIdx.x;
    float v[3]; float s = 0.f, sq = 0.f;
#pragma unroll
    for (int j = 0; j < 3; ++j) {
        int c = tid + j * 256;
        v[j] = py[(size_t)(gy + ys) * DMODEL + c] + px[(size_t)(gx + xs) * DMODEL + c];
        s += v[j]; sq += v[j] * v[j];
    }
#pragma unroll
    for (int off = 32; off >= 1; off >>= 1) { s += __shfl_down(s, off); sq += __shfl_down(sq, off); }
    __shared__ float red[8];
    if ((tid & 63) == 0) { red[tid >> 6] = s; red[4 + (tid >> 6)] = sq; }
    __syncthreads();
    float S = red[0] + red[1] + red[2] + red[3];
    float Q = red[4] + red[5] + red[6] + red[7];
    float mean = S * (1.f / DMODEL);
    float var = Q * (1.f / DMODEL) - mean * mean;
    float inv = rsqrtf(var + 1e-5f);
#pragma unroll
    for (int j = 0; j < 3; ++j) {
        int c = tid + j * 256;
        float y = (v[j] - mean) * inv * w[c] + b[c];
        posln[(size_t)row * DMODEL + c] = y;
        for (int bb = 0; bb < 16; ++bb)
            out2[((size_t)bb * SEQ + row) * DMODEL + c] = y;
    }
}

// ---------- deep-pipelined GEMM: C[M,N] = A[M,K] @ Bt[N,K]^T ----------
// tile 128x256, BK=64, 8 waves (2Mx4N, 64x64/wave), 3 LDS buffers, counted vmcnt.
#define EPI_CONV 0
#define EPI_QKV  1
#define EPI_FFN1 3
#define EPI_FFN2 4

template <int EPI>
__global__ __launch_bounds__(512, 2) void gemm3(const u16* __restrict__ A,
                                                const u16* __restrict__ Bt,
                                                float* __restrict__ outF,
                                                u16* __restrict__ outB,
                                                u16* __restrict__ outB2,
                                                u16* __restrict__ outB3,
                                                const float* __restrict__ bias,
                                                int M, int N, int K) {
    // per buffer: A [128][64] bf16 (16KB) + B [256][64] bf16 (32KB) = 48KB; x3 = 144KB
    __shared__ __align__(16) u16 lds[3 * 24576];
    const int tid = threadIdx.x;
    const int wave = tid >> 6, lane = tid & 63;
    const int c_lo = lane & 15, c_hi = lane >> 4;
    const int wm = wave >> 2, wn = wave & 3;
    const int m0 = blockIdx.x * 128, n0 = blockIdx.y * 256;

    // staging source coords: LDS is linear per gload_lds; global source is
    // pre-swizzled (inverse of the read-side XOR, which is an involution).
    int rowA[2], kkA[2], rowB[4], kkB[4];
#pragma unroll
    for (int r = 0; r < 2; ++r) {
        int L = r * 8192 + tid * 16;
        int P = L ^ ((L >> 3) & 0x70);
        rowA[r] = P >> 7; kkA[r] = (P & 127) >> 1;
    }
#pragma unroll
    for (int r = 0; r < 4; ++r) {
        int L = r * 8192 + tid * 16;
        int P = L ^ ((L >> 3) & 0x70);
        rowB[r] = P >> 7; kkB[r] = (P & 127) >> 1;
    }
    const int NT = K >> 6;
    f32x4 acc[4][4] = {};

    auto stage = [&](int t) {
        u16* buf = lds + (t % 3) * 24576;
        int k0 = t << 6;
#pragma unroll
        for (int r = 0; r < 2; ++r)
            gload_lds16(A + (size_t)(m0 + rowA[r]) * K + k0 + kkA[r],
                        buf + r * 4096 + wave * 512);
#pragma unroll
        for (int r = 0; r < 4; ++r)
            gload_lds16(Bt + (size_t)(n0 + rowB[r]) * K + k0 + kkB[r],
                        buf + 8192 + r * 4096 + wave * 512);
    };

    stage(0); stage(1);
    asm volatile("s_waitcnt vmcnt(6)" ::: "memory");
    __builtin_amdgcn_s_barrier();
    __builtin_amdgcn_sched_barrier(0);

    for (int t = 0; t < NT; ++t) {
        if (t + 2 < NT) stage(t + 2);
        const u16* Ab = lds + (t % 3) * 24576;
        const u16* Bb = Ab + 8192;
        s16x8 af[4][2], bf[4][2];
#pragma unroll
        for (int mf = 0; mf < 4; ++mf)
#pragma unroll
            for (int ks = 0; ks < 2; ++ks) {
                int by = (wm * 64 + mf * 16 + c_lo) * 128 + (ks * 32 + c_hi * 8) * 2;
                by ^= (by >> 3) & 0x70;
                af[mf][ks] = *(const s16x8*)((const char*)Ab + by);
            }
#pragma unroll
        for (int nf = 0; nf < 4; ++nf)
#pragma unroll
            for (int ks = 0; ks < 2; ++ks) {
                int by = (wn * 64 + nf * 16 + c_lo) * 128 + (ks * 32 + c_hi * 8) * 2;
                by ^= (by >> 3) & 0x70;
                bf[nf][ks] = *(const s16x8*)((const char*)Bb + by);
            }
        __builtin_amdgcn_s_setprio(1);
#pragma unroll
        for (int mf = 0; mf < 4; ++mf)
#pragma unroll
            for (int nf = 0; nf < 4; ++nf)
#pragma unroll
                for (int ks = 0; ks < 2; ++ks)
                    acc[mf][nf] = __builtin_amdgcn_mfma_f32_16x16x32_bf16(
                        af[mf][ks], bf[nf][ks], acc[mf][nf], 0, 0, 0);
        __builtin_amdgcn_s_setprio(0);
        if (t + 2 < NT) { asm volatile("s_waitcnt vmcnt(6)" ::: "memory"); }
        else            { asm volatile("s_waitcnt vmcnt(0)" ::: "memory"); }
        __builtin_amdgcn_s_barrier();
        __builtin_amdgcn_sched_barrier(0);
    }

#pragma unroll
    for (int mf = 0; mf < 4; ++mf)
#pragma unroll
        for (int nf = 0; nf < 4; ++nf)
#pragma unroll
            for (int r = 0; r < 4; ++r) {
                int grow = m0 + wm * 64 + mf * 16 + c_hi * 4 + r;
                int gcol = n0 + wn * 64 + nf * 16 + c_lo;
                float v = acc[mf][nf][r];
                if (EPI == EPI_CONV) {
                    v += bias[gcol]; v = fmaxf(v, 0.f);
                    outF[(size_t)grow * N + gcol] = v;
                } else if (EPI == EPI_QKV) {
                    int sel = n0 / 768;           // block lies fully in q/k/v section
                    int lcol = gcol - sel * 768;
                    if (sel == 0)      outB [(size_t)grow * 768 + lcol] = f2bf(v);
                    else if (sel == 1) outB2[(size_t)grow * 768 + lcol] = f2bf(v);
                    else {
                        int b = grow / SEQ, nt = grow % SEQ;
                        int h = lcol >> 6, dh = lcol & 63;
                        outB3[(size_t)(((b * NHEAD + h) << 6) + dh) * SEQ + nt] = f2bf(v);
                    }
                } else if (EPI == EPI_FFN1) {
                    v += bias[gcol]; v = fmaxf(v, 0.f);
                    outB[(size_t)grow * N + gcol] = f2bf(v);
                } else if (EPI == EPI_FFN2) {
                    outF[(size_t)grow * DMODEL + gcol] += v + bias[gcol];
                }
            }
}

// ---------- flash attention ----------
__global__ __launch_bounds__(256) void attn_kernel(const u16* __restrict__ Qb,
                                                   const u16* __restrict__ Kb,
                                                   const u16* __restrict__ Vt,
                                                   float* __restrict__ T) {
    int bid = blockIdx.x;
    int qt = bid % 9, h = (bid / 9) % NHEAD, b = bid / (9 * NHEAD);
    int q0 = qt * 64;
    const int tid = threadIdx.x, wave = tid >> 6, lane = tid & 63;
    const int c_lo = lane & 15, c_hi = lane >> 4;
    __shared__ __align__(16) u16 Qs[64][72];
    __shared__ __align__(16) u16 Ks[64][72];
    __shared__ __align__(16) u16 Vs[64][72];
    __shared__ __align__(16) u16 Ps[4][16][72];
#pragma unroll
    for (int i = 0; i < 2; ++i) {
        int c = i * 256 + tid, row = c >> 3, slot = (c & 7) * 8;
        *(s16x8*)&Qs[row][slot] =
            *(const s16x8*)(Qb + ((size_t)(b * SEQ + q0 + row) * DMODEL + h * HDIM + slot));
    }
    f32x4 o[4] = {};
    float mrun[4], lrun[4];
#pragma unroll
    for (int r = 0; r < 4; ++r) { mrun[r] = -1e30f; lrun[r] = 0.f; }
    for (int t2 = 0; t2 < 9; ++t2) {
        int kv0 = t2 * 64;
        __syncthreads();
#pragma unroll
        for (int i = 0; i < 2; ++i) {
            int c = i * 256 + tid, row = c >> 3, slot = (c & 7) * 8;
            *(s16x8*)&Ks[row][slot] =
                *(const s16x8*)(Kb + ((size_t)(b * SEQ + kv0 + row) * DMODEL + h * HDIM + slot));
            *(s16x8*)&Vs[row][slot] =
                *(const s16x8*)(Vt + ((size_t)((b * NHEAD + h) * HDIM + row) * SEQ + kv0 + slot));
        }
        __syncthreads();
        f32x4 s[4] = {};
        s16x8 aq[2];
#pragma unroll
        for (int ks = 0; ks < 2; ++ks)
            aq[ks] = *(const s16x8*)&Qs[wave * 16 + c_lo][ks * 32 + c_hi * 8];
#pragma unroll
        for (int nf = 0; nf < 4; ++nf)
#pragma unroll
            for (int ks = 0; ks < 2; ++ks) {
                s16x8 bk = *(const s16x8*)&Ks[nf * 16 + c_lo][ks * 32 + c_hi * 8];
                s[nf] = __builtin_amdgcn_mfma_f32_16x16x32_bf16(aq[ks], bk, s[nf], 0, 0, 0);
            }
#pragma unroll
        for (int nf = 0; nf < 4; ++nf)
#pragma unroll
            for (int r = 0; r < 4; ++r) s[nf][r] *= 0.125f;
        float mx[4];
#pragma unroll
        for (int r = 0; r < 4; ++r)
            mx[r] = fmaxf(fmaxf(s[0][r], s[1][r]), fmaxf(s[2][r], s[3][r]));
#pragma unroll
        for (int off = 1; off < 16; off <<= 1)
#pragma unroll
            for (int r = 0; r < 4; ++r) mx[r] = fmaxf(mx[r], __shfl_xor(mx[r], off));
        float alpha[4];
#pragma unroll
        for (int r = 0; r < 4; ++r) {
            float mn = fmaxf(mrun[r], mx[r]);
            alpha[r] = __expf(mrun[r] - mn);
            mrun[r] = mn;
            lrun[r] *= alpha[r];
        }
        float ls[4] = {0.f, 0.f, 0.f, 0.f};
        u16 pb[4][4];
#pragma unroll
        for (int nf = 0; nf < 4; ++nf)
#pragma unroll
            for (int r = 0; r < 4; ++r) {
                float p = __expf(s[nf][r] - mrun[r]);
                ls[r] += p;
                pb[nf][r] = f2bf(p);
            }
#pragma unroll
        for (int off = 1; off < 16; off <<= 1)
#pragma unroll
            for (int r = 0; r < 4; ++r) ls[r] += __shfl_xor(ls[r], off);
#pragma unroll
        for (int r = 0; r < 4; ++r) lrun[r] += ls[r];
#pragma unroll
        for (int df = 0; df < 4; ++df)
#pragma unroll
            for (int r = 0; r < 4; ++r) o[df][r] *= alpha[r];
#pragma unroll
        for (int nf = 0; nf < 4; ++nf)
#pragma unroll
            for (int r = 0; r < 4; ++r)
                Ps[wave][c_hi * 4 + r][c_lo + nf * 16] = pb[nf][r];
        asm volatile("s_waitcnt lgkmcnt(0)" ::: "memory");
        s16x8 pa[2];
#pragma unroll
        for (int ks = 0; ks < 2; ++ks)
            pa[ks] = *(const s16x8*)&Ps[wave][c_lo][ks * 32 + c_hi * 8];
#pragma unroll
        for (int df = 0; df < 4; ++df)
#pragma unroll
            for (int ks = 0; ks < 2; ++ks) {
                s16x8 bv = *(const s16x8*)&Vs[df * 16 + c_lo][ks * 32 + c_hi * 8];
                o[df] = __builtin_amdgcn_mfma_f32_16x16x32_bf16(pa[ks], bv, o[df], 0, 0, 0);
            }
    }
#pragma unroll
    for (int df = 0; df < 4; ++df)
#pragma unroll
        for (int r = 0; r < 4; ++r) {
            int grow = b * SEQ + q0 + wave * 16 + c_hi * 4 + r;
            int gcol = h * HDIM + df * 16 + c_lo;
            T[(size_t)grow * DMODEL + gcol] += o[df][r] / lrun[r];
        }
}

// ---------- host ----------
extern "C" void kernel_launch(void* const* d_in, const int* in_sizes, int n_in,
                              void* d_out, int out_size, void* d_ws, size_t ws_size,
                              hipStream_t stream) {
    (void)in_sizes; (void)n_in; (void)out_size; (void)ws_size;
    const float* x        = (const float*)d_in[0];
    const float* conv_w   = (const float*)d_in[1];
    const float* conv_b   = (const float*)d_in[2];
    const float* ln_w     = (const float*)d_in[3];
    const float* ln_b     = (const float*)d_in[4];
    const float* pos_y    = (const float*)d_in[5];
    const float* pos_x    = (const float*)d_in[6];
    const float* mha_ln_w = (const float*)d_in[7];
    const float* mha_ln_b = (const float*)d_in[8];
    const float* qw       = (const float*)d_in[9];
    const float* kw       = (const float*)d_in[10];
    const float* vw       = (const float*)d_in[11];
    const float* ffn_ln_w = (const float*)d_in[12];
    const float* ffn_ln_b = (const float*)d_in[13];
    const float* w1       = (const float*)d_in[14];
    const float* b1       = (const float*)d_in[15];
    const float* w2       = (const float*)d_in[16];
    const float* b2       = (const float*)d_in[17];
    const int*   xs       = (const int*)d_in[18];
    const int*   ys       = (const int*)d_in[19];
    float* out1 = (float*)d_out;
    float* out2 = out1 + (size_t)NTOK * DMODEL;

    size_t off = 0;
    char* ws = (char*)d_ws;
    auto carve = [&](size_t bytes) { char* p = ws + off; off += (bytes + 255) & ~(size_t)255; return p; };
    u16* wTqkv = (u16*)carve((size_t)3 * 768 * 768 * 2);   // q rows 0-767, k 768-1535, v 1536-2303
    u16* w1T = (u16*)carve((size_t)DFF * DMODEL * 2);
    u16* w2T = (u16*)carve((size_t)DMODEL * DFF * 2);
    float* t  = (float*)carve((size_t)NTOK * DMODEL * 4);
    u16* tl   = (u16*)carve((size_t)NTOK * DMODEL * 2);
    u16* qb   = (u16*)carve((size_t)NTOK * DMODEL * 2);
    u16* kb   = (u16*)carve((size_t)NTOK * DMODEL * 2);
    u16* vT   = (u16*)carve((size_t)NTOK * DMODEL * 2);
    u16* hb   = (u16*)carve((size_t)NTOK * DFF * 2);
    float* posln = (float*)carve((size_t)SEQ * DMODEL * 4);
    u16* wTq = wTqkv;
    u16* wTk = wTqkv + (size_t)768 * 768;
    u16* wTv = wTqkv + (size_t)2 * 768 * 768;
    u16* cw   = wTqkv;  // alias: conv weight bf16 (pre-loop only)
    u16* im2c = hb;     // alias: im2col (pre-loop only)

    convert_bf16_kernel<<<1152, 256, 0, stream>>>(conv_w, cw, 768 * 768);
    im2col_kernel<<<NTOK, 256, 0, stream>>>(x, im2c);
    gemm3<EPI_CONV><<<dim3(72, 3), 512, 0, stream>>>(im2c, cw, t, nullptr, nullptr, nullptr,
                                                     conv_b, NTOK, DMODEL, DMODEL);
    pos_ln_kernel<<<SEQ, 256, 0, stream>>>(pos_y, pos_x, ln_w, ln_b, xs, ys, posln, out2);
    ln_add_pos_kernel<<<NTOK, 256, 0, stream>>>(t, ln_w, ln_b, posln);

    for (int i = 0; i < 12; ++i) {
        transpose_layer_kernel<<<6336, 256, 0, stream>>>(
            qw + (size_t)i * 768 * 768, kw + (size_t)i * 768 * 768, vw + (size_t)i * 768 * 768,
            w1 + (size_t)i * 768 * DFF, w2 + (size_t)i * DFF * 768,
            wTq, wTk, wTv, w1T, w2T);
        ln_bf16_kernel<<<NTOK, 256, 0, stream>>>(t, mha_ln_w + i * DMODEL, mha_ln_b + i * DMODEL, tl);
        gemm3<EPI_QKV><<<dim3(72, 9), 512, 0, stream>>>(tl, wTqkv, nullptr, qb, kb, vT,
                                                        nullptr, NTOK, 3 * DMODEL, DMODEL);
        attn_kernel<<<16 * NHEAD * 9, 256, 0, stream>>>(qb, kb, vT, t);
        ln_bf16_kernel<<<NTOK, 256, 0, stream>>>(t, ffn_ln_w + i * DMODEL, ffn_ln_b + i * DMODEL, tl);
        gemm3<EPI_FFN1><<<dim3(72, 12), 512, 0, stream>>>(tl, w1T, nullptr, hb, nullptr, nullptr,
                                                          b1 + (size_t)i * DFF, NTOK, DFF, DMODEL);
        gemm3<EPI_FFN2><<<dim3(72, 3), 512, 0, stream>>>(hb, w2T, t, nullptr, nullptr, nullptr,
                                                         b2 + (size_t)i * DMODEL, NTOK, DMODEL, DFF);
    }
    copy_f32_kernel<<<2048, 256, 0, stream>>>(t, out1, (NTOK * DMODEL) / 4);
}